// Round 1
// baseline (410.049 us; speedup 1.0000x reference)
//
#include <hip/hip_runtime.h>
#include <math.h>

#define MN_EPS 1e-4f

// ---------------------------------------------------------------------------
// Kernel 1: per-block partial per-channel sums / sums-of-squares over a
// contiguous stripe of rows. Block = C/4 threads, each thread owns one float4
// (4 channels). Masked-out rows are skipped entirely (mask is wave-uniform
// per row -> scalar branch, saves ~half the read traffic).
// ---------------------------------------------------------------------------
__global__ void __launch_bounds__(256) mn_stats(
    const float4* __restrict__ y4, const int* __restrict__ mask,
    float4* __restrict__ pSum, float4* __restrict__ pSq,
    float* __restrict__ pCnt, int rowsPerBlock, int C4)
{
    const int tid = threadIdx.x;
    const int b = blockIdx.x;
    const long r0 = (long)b * rowsPerBlock;
    float4 s = make_float4(0.f, 0.f, 0.f, 0.f);
    float4 q = make_float4(0.f, 0.f, 0.f, 0.f);
    int cnt = 0;
    for (int i = 0; i < rowsPerBlock; ++i) {
        const long r = r0 + i;
        if (mask[r] > 0) {
            ++cnt;
            const float4 v = y4[r * C4 + tid];
            s.x += v.x; s.y += v.y; s.z += v.z; s.w += v.w;
            q.x = fmaf(v.x, v.x, q.x);
            q.y = fmaf(v.y, v.y, q.y);
            q.z = fmaf(v.z, v.z, q.z);
            q.w = fmaf(v.w, v.w, q.w);
        }
    }
    pSum[(long)b * C4 + tid] = s;
    pSq [(long)b * C4 + tid] = q;
    if (tid == 0) pCnt[b] = (float)cnt;
}

// ---------------------------------------------------------------------------
// Kernel 2: reduce P partials per channel, compute n, then the fused affine
// coefficients: a[c] = gamma[c]/(std[c]+eps), b[c] = beta[c] - mean[c]*a[c].
// ---------------------------------------------------------------------------
__global__ void __launch_bounds__(256) mn_finalize(
    const float* __restrict__ pSum, const float* __restrict__ pSq,
    const float* __restrict__ pCnt,
    const float* __restrict__ gamma, const float* __restrict__ beta,
    float* __restrict__ aArr, float* __restrict__ bArr, int P, int C)
{
    __shared__ float sCnt[256];
    const int tid = threadIdx.x;

    // block-wide reduction of the valid-token count
    float lc = 0.f;
    for (int p = tid; p < P; p += 256) lc += pCnt[p];
    sCnt[tid] = lc;
    __syncthreads();
    for (int off = 128; off > 0; off >>= 1) {
        if (tid < off) sCnt[tid] += sCnt[tid + off];
        __syncthreads();
    }
    const float n = sCnt[0];

    const int c = blockIdx.x * 256 + tid;
    if (c < C) {
        float s = 0.f, q = 0.f;
        for (int p = 0; p < P; ++p) {
            s += pSum[(size_t)p * C + c];
            q += pSq [(size_t)p * C + c];
        }
        const float mean = s / n;
        float var = (q - s * s / n) / (n - 1.0f);
        var = fmaxf(var, 0.0f);
        const float inv = 1.0f / (sqrtf(var) + MN_EPS);
        const float A = gamma[c] * inv;
        aArr[c] = A;
        bArr[c] = beta[c] - mean * A;
    }
}

// ---------------------------------------------------------------------------
// Kernel 3: out[r][c] = mask[r] ? a[c]*y[r][c] + b[c] : y[r][c]
// a4/b4 are loop-invariant registers (thread's channels fixed across rows).
// ---------------------------------------------------------------------------
__global__ void __launch_bounds__(256) mn_apply(
    const float4* __restrict__ y4, const int* __restrict__ mask,
    const float4* __restrict__ aArr4, const float4* __restrict__ bArr4,
    float4* __restrict__ out4, int R, int C4)
{
    const int tid = threadIdx.x;
    const float4 A = aArr4[tid];
    const float4 Bv = bArr4[tid];
    for (int r = blockIdx.x; r < R; r += gridDim.x) {
        const float4 v = y4[(long)r * C4 + tid];
        float4 o;
        if (mask[r] > 0) {
            o.x = fmaf(A.x, v.x, Bv.x);
            o.y = fmaf(A.y, v.y, Bv.y);
            o.z = fmaf(A.z, v.z, Bv.z);
            o.w = fmaf(A.w, v.w, Bv.w);
        } else {
            o = v;
        }
        out4[(long)r * C4 + tid] = o;
    }
}

extern "C" void kernel_launch(void* const* d_in, const int* in_sizes, int n_in,
                              void* d_out, int out_size, void* d_ws, size_t ws_size,
                              hipStream_t stream)
{
    const float* y     = (const float*)d_in[0];
    const int*   mask  = (const int*)  d_in[1];
    const float* gamma = (const float*)d_in[2];
    const float* beta  = (const float*)d_in[3];
    float* out = (float*)d_out;

    const int R  = in_sizes[1];   // B*T (mask element count)
    const int C  = in_sizes[2];   // channels (gamma element count)
    const int C4 = C / 4;         // 256 for C=1024

    // Pick the largest partial-count P whose workspace fits.
    int P = 512;
    while (P > 1) {
        const size_t need = ((size_t)2 * P * C + P + 2 * C) * sizeof(float);
        if (need <= ws_size && (R % P) == 0) break;
        P >>= 1;
    }
    const int rowsPerBlock = R / P;

    float* w    = (float*)d_ws;
    float* pSum = w;
    float* pSq  = pSum + (size_t)P * C;
    float* pCnt = pSq  + (size_t)P * C;
    float* aArr = pCnt + P;
    float* bArr = aArr + C;

    mn_stats<<<P, C4, 0, stream>>>((const float4*)y, mask,
                                   (float4*)pSum, (float4*)pSq, pCnt,
                                   rowsPerBlock, C4);

    const int fb = (C + 255) / 256;
    mn_finalize<<<fb, 256, 0, stream>>>(pSum, pSq, pCnt, gamma, beta,
                                        aArr, bArr, P, C);

    mn_apply<<<2048, C4, 0, stream>>>((const float4*)y, mask,
                                      (const float4*)aArr, (const float4*)bArr,
                                      (float4*)out, R, C4);
}

// Round 2
// 264.253 us; speedup vs baseline: 1.5517x; 1.5517x over previous
//
#include <hip/hip_runtime.h>
#include <math.h>

#define MN_EPS 1e-4f

__device__ inline void f4add(float4& a, const float4& b) {
    a.x += b.x; a.y += b.y; a.z += b.z; a.w += b.w;
}

// ---------------------------------------------------------------------------
// Kernel 1: per-block partial per-channel sums / sums-of-squares over a
// contiguous stripe of rows. Block = C/4 threads, each thread owns one float4
// (4 channels). Mask for the stripe is staged in LDS in chunks so the per-row
// branch is LDS-latency, not HBM-latency. Masked-out rows are skipped
// entirely (saves ~half the pass-1 read traffic).
// ---------------------------------------------------------------------------
#define MN_CHUNK 256
__global__ void __launch_bounds__(256) mn_stats(
    const float4* __restrict__ y4, const int* __restrict__ mask,
    float4* __restrict__ pSum, float4* __restrict__ pSq,
    float* __restrict__ pCnt, int rowsPerBlock, int C4)
{
    __shared__ int sMask[MN_CHUNK];
    const int tid = threadIdx.x;
    const int b = blockIdx.x;
    const long r0 = (long)b * rowsPerBlock;
    float4 s = make_float4(0.f, 0.f, 0.f, 0.f);
    float4 q = make_float4(0.f, 0.f, 0.f, 0.f);
    int cnt = 0;
    for (int base = 0; base < rowsPerBlock; base += MN_CHUNK) {
        const int mrows = min(MN_CHUNK, rowsPerBlock - base);
        __syncthreads();  // protect sMask reuse
        for (int t = tid; t < mrows; t += blockDim.x)
            sMask[t] = mask[r0 + base + t];
        __syncthreads();
        for (int i = 0; i < mrows; ++i) {
            if (sMask[i] > 0) {
                ++cnt;
                const float4 v = y4[(r0 + base + i) * C4 + tid];
                s.x += v.x; s.y += v.y; s.z += v.z; s.w += v.w;
                q.x = fmaf(v.x, v.x, q.x);
                q.y = fmaf(v.y, v.y, q.y);
                q.z = fmaf(v.z, v.z, q.z);
                q.w = fmaf(v.w, v.w, q.w);
            }
        }
    }
    pSum[(long)b * C4 + tid] = s;
    pSq [(long)b * C4 + tid] = q;
    if (tid == 0) pCnt[b] = (float)cnt;
}

// ---------------------------------------------------------------------------
// Kernel 2: one block per float4-of-channels (grid = C4). 256 threads stripe
// over the P partials, LDS tree-reduce, then thread 0 computes the fused
// affine coefficients a[c] = gamma/(std+eps), b[c] = beta - mean*a.
// ---------------------------------------------------------------------------
__global__ void __launch_bounds__(256) mn_finalize(
    const float4* __restrict__ pSum4, const float4* __restrict__ pSq4,
    const float* __restrict__ pCnt,
    const float4* __restrict__ gamma4, const float4* __restrict__ beta4,
    float4* __restrict__ aArr4, float4* __restrict__ bArr4, int P, int C4)
{
    __shared__ float4 sS[256];
    __shared__ float4 sQ[256];
    __shared__ float  sN[256];
    const int tid = threadIdx.x;
    const int c4 = blockIdx.x;

    float4 s = make_float4(0.f, 0.f, 0.f, 0.f);
    float4 q = make_float4(0.f, 0.f, 0.f, 0.f);
    float  n = 0.f;
    for (int p = tid; p < P; p += 256) {
        f4add(s, pSum4[(size_t)p * C4 + c4]);
        f4add(q, pSq4 [(size_t)p * C4 + c4]);
        n += pCnt[p];
    }
    sS[tid] = s; sQ[tid] = q; sN[tid] = n;
    __syncthreads();
    for (int off = 128; off > 0; off >>= 1) {
        if (tid < off) {
            f4add(sS[tid], sS[tid + off]);
            f4add(sQ[tid], sQ[tid + off]);
            sN[tid] += sN[tid + off];
        }
        __syncthreads();
    }
    if (tid == 0) {
        const float nn = sN[0];
        const float4 S = sS[0];
        const float4 Q = sQ[0];
        const float4 G = gamma4[c4];
        const float4 Bt = beta4[c4];
        float4 A, Bo;
        {
            const float mean = S.x / nn;
            float var = (Q.x - S.x * S.x / nn) / (nn - 1.0f);
            var = fmaxf(var, 0.0f);
            A.x = G.x / (sqrtf(var) + MN_EPS);
            Bo.x = Bt.x - mean * A.x;
        }
        {
            const float mean = S.y / nn;
            float var = (Q.y - S.y * S.y / nn) / (nn - 1.0f);
            var = fmaxf(var, 0.0f);
            A.y = G.y / (sqrtf(var) + MN_EPS);
            Bo.y = Bt.y - mean * A.y;
        }
        {
            const float mean = S.z / nn;
            float var = (Q.z - S.z * S.z / nn) / (nn - 1.0f);
            var = fmaxf(var, 0.0f);
            A.z = G.z / (sqrtf(var) + MN_EPS);
            Bo.z = Bt.z - mean * A.z;
        }
        {
            const float mean = S.w / nn;
            float var = (Q.w - S.w * S.w / nn) / (nn - 1.0f);
            var = fmaxf(var, 0.0f);
            A.w = G.w / (sqrtf(var) + MN_EPS);
            Bo.w = Bt.w - mean * A.w;
        }
        aArr4[c4] = A;
        bArr4[c4] = Bo;
    }
}

// ---------------------------------------------------------------------------
// Kernel 3: out[r][c] = mask[r] ? a[c]*y[r][c] + b[c] : y[r][c]
// a4/b4 are loop-invariant registers (thread's channels fixed across rows).
// ---------------------------------------------------------------------------
__global__ void __launch_bounds__(256) mn_apply(
    const float4* __restrict__ y4, const int* __restrict__ mask,
    const float4* __restrict__ aArr4, const float4* __restrict__ bArr4,
    float4* __restrict__ out4, int R, int C4)
{
    const int tid = threadIdx.x;
    const float4 A = aArr4[tid];
    const float4 Bv = bArr4[tid];
    for (int r = blockIdx.x; r < R; r += gridDim.x) {
        const float4 v = y4[(long)r * C4 + tid];
        float4 o;
        if (mask[r] > 0) {
            o.x = fmaf(A.x, v.x, Bv.x);
            o.y = fmaf(A.y, v.y, Bv.y);
            o.z = fmaf(A.z, v.z, Bv.z);
            o.w = fmaf(A.w, v.w, Bv.w);
        } else {
            o = v;
        }
        out4[(long)r * C4 + tid] = o;
    }
}

extern "C" void kernel_launch(void* const* d_in, const int* in_sizes, int n_in,
                              void* d_out, int out_size, void* d_ws, size_t ws_size,
                              hipStream_t stream)
{
    const float* y     = (const float*)d_in[0];
    const int*   mask  = (const int*)  d_in[1];
    const float* gamma = (const float*)d_in[2];
    const float* beta  = (const float*)d_in[3];
    float* out = (float*)d_out;

    const int R  = in_sizes[1];   // B*T (mask element count)
    const int C  = in_sizes[2];   // channels (gamma element count)
    const int C4 = C / 4;         // 256 for C=1024

    // Pick the largest partial-count P whose workspace fits.
    int P = 1024;
    while (P > 1) {
        const size_t need = ((size_t)2 * P * C + P + 2 * C) * sizeof(float);
        if (need <= ws_size && (R % P) == 0) break;
        P >>= 1;
    }
    const int rowsPerBlock = R / P;

    float* w    = (float*)d_ws;
    float* pSum = w;
    float* pSq  = pSum + (size_t)P * C;
    float* pCnt = pSq  + (size_t)P * C;
    float* aArr = pCnt + P;
    float* bArr = aArr + C;

    mn_stats<<<P, C4, 0, stream>>>((const float4*)y, mask,
                                   (float4*)pSum, (float4*)pSq, pCnt,
                                   rowsPerBlock, C4);

    mn_finalize<<<C4, 256, 0, stream>>>((const float4*)pSum, (const float4*)pSq,
                                        pCnt, (const float4*)gamma,
                                        (const float4*)beta,
                                        (float4*)aArr, (float4*)bArr, P, C4);

    mn_apply<<<2048, C4, 0, stream>>>((const float4*)y, mask,
                                      (const float4*)aArr, (const float4*)bArr,
                                      (float4*)out, R, C4);
}